// Round 9
// baseline (169.664 us; speedup 1.0000x reference)
//
#include <hip/hip_runtime.h>
#include <hip/hip_fp16.h>

#define N_SIG (1 << 23)   // 8388608
#define N2    (1 << 24)   // padded FFT length = 256^3
#define MH    (1 << 23)   // half length M = 2^23 = 256*256*128

// ---------------------------------------------------------------------------
// complex helpers
// ---------------------------------------------------------------------------
__device__ __forceinline__ float2 cadd(float2 a, float2 b) { return make_float2(a.x + b.x, a.y + b.y); }
__device__ __forceinline__ float2 csub(float2 a, float2 b) { return make_float2(a.x - b.x, a.y - b.y); }
__device__ __forceinline__ float2 cmul(float2 a, float2 b) {
    return make_float2(fmaf(a.x, b.x, -(a.y * b.y)), fmaf(a.x, b.y, a.y * b.x));
}
__device__ __forceinline__ float2 mulnegi(float2 a) { return make_float2(a.y, -a.x); }  // -i*a

__device__ __forceinline__ float2 h2f(__half2 h) { return __half22float2(h); }
__device__ __forceinline__ __half2 f2h(float2 f) { return __float22half2_rn(f); }

// exp(-2*pi*i*f), f in revolutions (v_sin/v_cos take revolutions, |f| < 256 ok)
__device__ __forceinline__ float2 twid(float f) {
    float s, c;
#if __has_builtin(__builtin_amdgcn_sinf) && __has_builtin(__builtin_amdgcn_cosf)
    s = __builtin_amdgcn_sinf(f);
    c = __builtin_amdgcn_cosf(f);
#else
    __sincosf(6.28318530717958647693f * f, &s, &c);
#endif
    return make_float2(c, -s);
}

// radix-4 DIF butterfly = natural-order 4-point DFT (negative exponent)
__device__ __forceinline__ void bfly4(float2 c0, float2 c1, float2 c2, float2 c3,
                                      float2& e0, float2& e1, float2& e2, float2& e3) {
    float2 d0 = cadd(c0, c2), d1 = csub(c0, c2);
    float2 d2 = cadd(c1, c3), d3 = mulnegi(csub(c1, c3));
    e0 = cadd(d0, d2); e1 = cadd(d1, d3); e2 = csub(d0, d2); e3 = csub(d1, d3);
}

// 16-point DFT, natural order in/out
__device__ __forceinline__ void fft16(float2 v[16]) {
    const float C1 = 0.92387953251128675613f;
    const float S1 = 0.38268343236508977173f;
    const float RH = 0.70710678118654752440f;
    const float2 W1 = make_float2( C1, -S1);
    const float2 W2 = make_float2( RH, -RH);
    const float2 W3 = make_float2( S1, -C1);
    const float2 W6 = make_float2(-RH, -RH);
    const float2 W9 = make_float2(-C1,  S1);
    float2 t[16];
    { float2 e0,e1,e2,e3; bfly4(v[0],v[4],v[8],v[12], e0,e1,e2,e3);
      t[0]=e0; t[1]=e1; t[2]=e2; t[3]=e3; }
    { float2 e0,e1,e2,e3; bfly4(v[1],v[5],v[9],v[13], e0,e1,e2,e3);
      t[4]=e0; t[5]=cmul(e1,W1); t[6]=cmul(e2,W2); t[7]=cmul(e3,W3); }
    { float2 e0,e1,e2,e3; bfly4(v[2],v[6],v[10],v[14], e0,e1,e2,e3);
      t[8]=e0; t[9]=cmul(e1,W2); t[10]=mulnegi(e2); t[11]=cmul(e3,W6); }
    { float2 e0,e1,e2,e3; bfly4(v[3],v[7],v[11],v[15], e0,e1,e2,e3);
      t[12]=e0; t[13]=cmul(e1,W3); t[14]=cmul(e2,W6); t[15]=cmul(e3,W9); }
    { float2 e0,e1,e2,e3; bfly4(t[0],t[4],t[8],t[12], e0,e1,e2,e3);
      v[0]=e0; v[4]=e1; v[8]=e2; v[12]=e3; }
    { float2 e0,e1,e2,e3; bfly4(t[1],t[5],t[9],t[13], e0,e1,e2,e3);
      v[1]=e0; v[5]=e1; v[9]=e2; v[13]=e3; }
    { float2 e0,e1,e2,e3; bfly4(t[2],t[6],t[10],t[14], e0,e1,e2,e3);
      v[2]=e0; v[6]=e1; v[10]=e2; v[14]=e3; }
    { float2 e0,e1,e2,e3; bfly4(t[3],t[7],t[11],t[15], e0,e1,e2,e3);
      v[3]=e0; v[7]=e1; v[11]=e2; v[15]=e3; }
}

// 8-point DFT, natural order in/out
__device__ __forceinline__ void fft8(float2 v[8]) {
    const float RH = 0.70710678118654752440f;
    float2 e0,e1,e2,e3, o0,o1,o2,o3;
    bfly4(v[0],v[2],v[4],v[6], e0,e1,e2,e3);
    bfly4(v[1],v[3],v[5],v[7], o0,o1,o2,o3);
    o1 = cmul(o1, make_float2( RH,-RH));
    o2 = mulnegi(o2);
    o3 = cmul(o3, make_float2(-RH,-RH));
    v[0]=cadd(e0,o0); v[4]=csub(e0,o0);
    v[1]=cadd(e1,o1); v[5]=csub(e1,o1);
    v[2]=cadd(e2,o2); v[6]=csub(e2,o2);
    v[3]=cadd(e3,o3); v[7]=csub(e3,o3);
}

// Scaled W for stored Z_s = Z * 2^-2: returns W * 2^-14
__device__ __forceinline__ float2 Wfun_s(float2 sk, float2 sr) {
    float ax = sk.x*sk.x - sk.y*sk.y, ay = 2.f*sk.x*sk.y;
    float bx = sr.x*sr.x - sr.y*sr.y, by = -2.f*sr.x*sr.y;
    float dx = ax - bx, dy = ay - by;
    const float C = 1.0f / 4096.0f;   // 2^-12
    return make_float2(C*dy, -C*dx);
}

// ---------------------------------------------------------------------------
// MODE 0: fwd stage A  (N2, radix-256, l=65536), pack fused, staged j-major out
// MODE 1: fwd stage B  (N2, radix-256, l=256),  direct k-major store
// MODE 3: inv stage A  (M,  radix-256, l=32768), staged, amp 2^-4 in twiddle
// MODE 4: inv stage B  (M,  radix-256, l=128),  direct store, amp 2^-4
// MODE 5: inv stage C  (M,  radix-128, l=1),    fp32 interleaved-real out, *0.5
// Unphased half2 transpose in 32 KiB LDS, full ^row swizzle.
// Barriers: MODE 1/4/5 = 1; MODE 0/3 = 3.
// ---------------------------------------------------------------------------
template<int MODE>
__global__ __launch_bounds__(512, 4)
void fft_pass(const float* __restrict__ ga, const float* __restrict__ gx,
              const __half2* __restrict__ gin, __half2* __restrict__ gout,
              float2* __restrict__ goutF) {
    __shared__ __half2 tile[8192];   // 32 KB
    const int t   = threadIdx.x;
    const int blk = blockIdx.x;

    if constexpr (MODE == 5) {
        // ---- radix-128 final pass: 64 rows x 128 pts, slot in [0,8) ----
        const int row  = t & 63;
        const int slot = t >> 6;
        const int swz  = row & 31;
        const int bi   = blk * 64 + row;

        float2 va[8], vb[8];
        #pragma unroll
        for (int u2 = 0; u2 < 8; ++u2)
            va[u2] = h2f(gin[bi + ((slot + 16 * u2) << 16)]);
        #pragma unroll
        for (int u2 = 0; u2 < 8; ++u2)
            vb[u2] = h2f(gin[bi + ((slot + 8 + 16 * u2) << 16)]);
        fft8(va); fft8(vb);
        {   // layer-1 twiddles via recurrence (chain <= 7)
            float2 w1a = twid((float)slot * (1.0f / 128.0f));
            float2 w1b = twid((float)(slot + 8) * (1.0f / 128.0f));
            float2 ca = w1a, cb = w1b;
            va[1] = cmul(va[1], ca); vb[1] = cmul(vb[1], cb);
            #pragma unroll
            for (int r2 = 2; r2 < 8; ++r2) {
                ca = cmul(ca, w1a); va[r2] = cmul(va[r2], ca);
                cb = cmul(cb, w1b); vb[r2] = cmul(vb[r2], cb);
            }
        }
        #pragma unroll
        for (int r2 = 0; r2 < 8; ++r2) {
            tile[row * 128 + ((slot + 16 * r2) ^ swz)] = f2h(va[r2]);
            tile[row * 128 + ((slot + 8 + 16 * r2) ^ swz)] = f2h(vb[r2]);
        }
        __syncthreads();
        float2 w[16];
        #pragma unroll
        for (int q1 = 0; q1 < 16; ++q1)
            w[q1] = h2f(tile[row * 128 + ((q1 + 16 * slot) ^ swz)]);
        fft16(w);   // w[r1] -> output r = slot + 8*r1

        const float sc = 0.5f;          // accumulated scale 2^-22; y = G/2^23
        const int k0 = blk * 64;
        #pragma unroll
        for (int r1 = 0; r1 < 8; ++r1) {
            int r = slot + 8 * r1;      // < 64
            goutF[k0 + row + (r << 16)] = make_float2(w[r1].x * sc, -w[r1].y * sc);
        }
        return;
    } else {
        // ---- radix-256 pass: 32 rows x 256 pts, slot in [0,16) ----
        const int row  = t & 31;
        const int slot = t >> 5;
        float2 v[16];
        int jt = 0;

        if constexpr (MODE == 0) {          // fwd A, pack fused (q>=128 zero)
            int j = blk * 32 + row;
            jt = j;
            #pragma unroll
            for (int u2 = 0; u2 < 16; ++u2) {
                if (u2 < 8) {
                    int g = j + ((slot + 16 * u2) << 16);   // < N_SIG
                    v[u2] = make_float2(ga[g], gx[g]);
                } else {
                    v[u2] = make_float2(0.f, 0.f);
                }
            }
        } else if constexpr (MODE == 3) {   // inv A: linear read of P_s
            int j = blk * 32 + row;
            jt = j;
            #pragma unroll
            for (int u2 = 0; u2 < 16; ++u2)
                v[u2] = h2f(gin[j + ((slot + 16 * u2) << 15)]);
        } else if constexpr (MODE == 1) {   // fwd B
            int jB = blk >> 3, k0 = (blk & 7) * 32;
            int bi = k0 + row + (jB << 8);
            jt = jB;
            #pragma unroll
            for (int u2 = 0; u2 < 16; ++u2)
                v[u2] = h2f(gin[bi + ((slot + 16 * u2) << 16)]);
        } else {                            // MODE 4: inv B (stride 2^15)
            int jB = blk >> 3, k0 = (blk & 7) * 32;
            int bi = k0 + row + (jB << 8);
            jt = jB;
            #pragma unroll
            for (int u2 = 0; u2 < 16; ++u2)
                v[u2] = h2f(gin[bi + ((slot + 16 * u2) << 15)]);
        }

        // layer 1: FFT16 over u2, twiddle W256^{slot*r}, reseed at r=8
        fft16(v);
        {
            float2 w1 = twid((float)slot * (1.0f / 256.0f));
            float2 w8 = twid((float)slot * (1.0f / 32.0f));
            float2 cw = w1;
            v[1] = cmul(v[1], cw);
            #pragma unroll
            for (int r = 2; r < 16; ++r) {
                cw = (r == 8) ? w8 : cmul(cw, w1);
                v[r] = cmul(v[r], cw);
            }
        }

        // unphased half2 transpose, ^row swizzle
        #pragma unroll
        for (int r = 0; r < 16; ++r)
            tile[row * 256 + ((slot + 16 * r) ^ row)] = f2h(v[r]);
        __syncthreads();
        float2 w[16];
        #pragma unroll
        for (int u1 = 0; u1 < 16; ++u1)
            w[u1] = h2f(tile[row * 256 + ((u1 + 16 * slot) ^ row)]);
        if constexpr (MODE == 0 || MODE == 3)
            __syncthreads();                 // readers done before staging overwrite

        fft16(w);

        // outer twiddle base*step^v2 (reseed at v2=8); MODE3/4 fold 2^-4 scale
        {
            float base_rev, step_rev, amp;
            if constexpr (MODE == 0) {       // D = 2^24
                base_rev = (float)(jt * slot) * (1.0f / 16777216.0f);
                step_rev = (float)jt * (1.0f / 1048576.0f);
                amp = 1.0f;
            } else if constexpr (MODE == 3) {// D = 2^23
                base_rev = (float)(jt * slot) * (1.0f / 8388608.0f);
                step_rev = (float)jt * (1.0f / 524288.0f);
                amp = 0.0625f;
            } else if constexpr (MODE == 1) {// D = 65536
                base_rev = (float)(jt * slot) * (1.0f / 65536.0f);
                step_rev = (float)jt * (1.0f / 4096.0f);
                amp = 1.0f;
            } else {                         // MODE 4: D = 32768
                base_rev = (float)(jt * slot) * (1.0f / 32768.0f);
                step_rev = (float)jt * (1.0f / 2048.0f);
                amp = 0.0625f;
            }
            float2 b0 = twid(base_rev);
            b0.x *= amp; b0.y *= amp;
            float2 os = twid(step_rev);
            float2 b8 = twid(base_rev + 8.0f * step_rev);
            b8.x *= amp; b8.y *= amp;
            float2 ob = b0;
            w[0] = cmul(w[0], ob);
            #pragma unroll
            for (int v2 = 1; v2 < 16; ++v2) {
                ob = (v2 == 8) ? b8 : cmul(ob, os);
                w[v2] = cmul(w[v2], ob);
            }
        }

        if constexpr (MODE == 0 || MODE == 3) {
            // j-major out[256 j + r]: stage half2, one linear sweep
            #pragma unroll
            for (int v2 = 0; v2 < 16; ++v2)
                tile[row * 256 + ((slot + 16 * v2) ^ row)] = f2h(w[v2]);
            __syncthreads();
            int base = blk << 13;
            #pragma unroll
            for (int i = 0; i < 16; ++i) {
                int s = t + 512 * i;
                int rr = s >> 8, c = s & 255;
                gout[base + s] = tile[rr * 256 + (c ^ (rr & 31))];
            }
        } else if constexpr (MODE == 1) {
            // k-major out[k + 65536 j + 256 r]: direct store
            int jB = blk >> 3, k0 = (blk & 7) * 32;
            int base = k0 + (jB << 16) + row;
            #pragma unroll
            for (int v2 = 0; v2 < 16; ++v2)
                gout[base + ((slot + 16 * v2) << 8)] = f2h(w[v2]);
        } else {   // MODE 4
            int jB = blk >> 3, k0 = (blk & 7) * 32;
            int base = k0 + (jB << 16) + row;
            #pragma unroll
            for (int v2 = 0; v2 < 16; ++v2)
                gout[base + ((slot + 16 * v2) << 8)] = f2h(w[v2]);
        }
    }
}

// ---------------------------------------------------------------------------
// Fused fwd stage C + Hermitian pointwise. Block b (1025 blocks) processes
// cols A = [32b, 32b+31] AND mirrors B = {(65505-32b+j) & 65535}. Both Z-tiles
// (col x 256, half2, scale 2^-2) end up in 64 KB LDS; pw reads the 4-tuples
// in-LDS and writes only P_s (= P * 2^-14). Overlapping blocks write identical
// bytes (benign). col 0's wrapped mirror handled via its own A-row.
// ---------------------------------------------------------------------------
__global__ __launch_bounds__(512, 4)
void fftC_pw(const __half2* __restrict__ gin, __half2* __restrict__ P) {
    __shared__ __half2 lds[16384];            // 64 KB: r0=[0,8192), r1=[8192,16384)
    const int t    = threadIdx.x;
    const int b    = blockIdx.x;              // [0, 1025)
    const int row  = t & 31;
    const int slot = t >> 5;

    const int colA = 32 * b + row;                        // <= 32799
    const int colB = (65505 - 32 * b + row) & 65535;      // mirror(colA(i)) = colB(31-i)

    float2 v[16], w[16];

    // ---- A layer 1 ----
    #pragma unroll
    for (int u2 = 0; u2 < 16; ++u2)
        v[u2] = h2f(gin[colA + ((slot + 16 * u2) << 16)]);
    fft16(v);
    {
        float2 w1 = twid((float)slot * (1.0f / 256.0f));
        float2 w8 = twid((float)slot * (1.0f / 32.0f));
        float2 cw = w1;
        v[1] = cmul(v[1], cw);
        #pragma unroll
        for (int r = 2; r < 16; ++r) { cw = (r == 8) ? w8 : cmul(cw, w1); v[r] = cmul(v[r], cw); }
    }
    #pragma unroll
    for (int r = 0; r < 16; ++r)
        lds[row * 256 + ((slot + 16 * r) ^ row)] = f2h(v[r]);
    __syncthreads();                                       // BAR 1

    // ---- A layer 2 (read r0); B loads issued for overlap ----
    #pragma unroll
    for (int u1 = 0; u1 < 16; ++u1)
        w[u1] = h2f(lds[row * 256 + ((u1 + 16 * slot) ^ row)]);
    #pragma unroll
    for (int u2 = 0; u2 < 16; ++u2)
        v[u2] = h2f(gin[colB + ((slot + 16 * u2) << 16)]);
    fft16(w);
    __half2 zA[16];                                        // Z_s = Z * 2^-2
    #pragma unroll
    for (int v2 = 0; v2 < 16; ++v2)
        zA[v2] = f2h(make_float2(w[v2].x * 0.25f, w[v2].y * 0.25f));

    // ---- B layer 1 ----
    fft16(v);
    {
        float2 w1 = twid((float)slot * (1.0f / 256.0f));
        float2 w8 = twid((float)slot * (1.0f / 32.0f));
        float2 cw = w1;
        v[1] = cmul(v[1], cw);
        #pragma unroll
        for (int r = 2; r < 16; ++r) { cw = (r == 8) ? w8 : cmul(cw, w1); v[r] = cmul(v[r], cw); }
    }
    __syncthreads();                                       // BAR 2: r0 reads done
    #pragma unroll
    for (int r = 0; r < 16; ++r)
        lds[8192 + row * 256 + ((slot + 16 * r) ^ row)] = f2h(v[r]);   // B transpose -> r1
    #pragma unroll
    for (int v2 = 0; v2 < 16; ++v2)
        lds[row * 256 + ((slot + 16 * v2) ^ row)] = zA[v2];            // Z_A -> r0
    __syncthreads();                                       // BAR 3

    // ---- B layer 2 (read r1) ----
    #pragma unroll
    for (int u1 = 0; u1 < 16; ++u1)
        w[u1] = h2f(lds[8192 + row * 256 + ((u1 + 16 * slot) ^ row)]);
    fft16(w);
    __syncthreads();                                       // BAR 4: r1 reads done
    #pragma unroll
    for (int v2 = 0; v2 < 16; ++v2)
        lds[8192 + row * 256 + ((slot + 16 * v2) ^ row)] =
            f2h(make_float2(w[v2].x * 0.25f, w[v2].y * 0.25f));        // Z_B -> r1
    __syncthreads();                                       // BAR 5

    // ---- pointwise from LDS ----
    const int jm = 31 - row;
    const bool c0 = (colA == 0);                           // block 0, row 0 only
    #pragma unroll
    for (int i = 0; i < 8; ++i) {
        int r  = slot + 16 * i;                            // [0,128)
        int tt = colA + (r << 16);                         // t in [0, M)
        float2 z1 = h2f(lds[row * 256 + (r ^ row)]);                 // Z[t]
        float2 z2 = h2f(lds[row * 256 + ((r + 128) ^ row)]);         // Z[t+M]
        float2 z3, z4;
        if (c0) {   // mirror wraps within col 0's own row
            z3 = h2f(lds[(256 - r) & 255]);                          // Z[0, (256-r)%256]
            z4 = h2f(lds[(128 - r) & 255]);                          // Z[0, (128-r)%256]
        } else {
            z3 = h2f(lds[8192 + jm * 256 + ((255 - r) ^ jm)]);       // Z[N2-t]
            z4 = h2f(lds[8192 + jm * 256 + ((127 - r) ^ jm)]);       // Z[M-t]
        }
        float2 Wt  = Wfun_s(z1, z3);                       // W[t]   * 2^-14
        float2 WtM = Wfun_s(z2, z4);                       // W[t+M] * 2^-14
        float2 e = twid((float)tt * (1.0f / 16777216.0f));
        float c = e.x, s = -e.y;                           // th = +2pi t / N2
        {
            float Sx = 0.5f*(Wt.x + WtM.x), Sy = 0.5f*(Wt.y + WtM.y);
            float Dx = 0.5f*(Wt.x - WtM.x), Dy = 0.5f*(Wt.y - WtM.y);
            float Tx = c*Dx - s*Dy, Ty = c*Dy + s*Dx;
            P[tt] = f2h(make_float2(Sx - Ty, -(Sy + Tx)));
        }
        if (tt > 0) {
            float2 Wt2  = Wfun_s(z4, z2);                  // W[M-t]  * 2^-14
            float2 Wt2M = Wfun_s(z3, z1);                  // W[N2-t] * 2^-14
            float Sx = 0.5f*(Wt2.x + Wt2M.x), Sy = 0.5f*(Wt2.y + Wt2M.y);
            float Dx = 0.5f*(Wt2.x - Wt2M.x), Dy = 0.5f*(Wt2.y - Wt2M.y);
            float Tx = -c*Dx - s*Dy, Ty = -c*Dy + s*Dx;    // e^{+2pi i (M-t)/N2} = (-c, s)
            P[MH - tt] = f2h(make_float2(Sx - Ty, -(Sy + Tx)));
        }
    }
}

extern "C" void kernel_launch(void* const* d_in, const int* in_sizes, int n_in,
                              void* d_out, int out_size, void* d_ws, size_t ws_size,
                              hipStream_t stream) {
    const float* a = (const float*)d_in[0];
    const float* x = (const float*)d_in[1];
    float2* out2 = (float2*)d_out;

    __half2* buf0 = (__half2*)d_ws;     // 64 MB
    __half2* buf1 = buf0 + N2;          // 64 MB

    dim3 b(512);
    // forward FFT of z = a + i*x, length 2^24
    fft_pass<0><<<2048, b, 0, stream>>>(a, x, nullptr, buf0, nullptr);
    fft_pass<1><<<2048, b, 0, stream>>>(nullptr, nullptr, buf0, buf1, nullptr);
    // fused fwd stage C + Hermitian pointwise: buf1 -> P_s in buf0
    fftC_pw<<<1025, b, 0, stream>>>(buf1, buf0);
    // inverse via half-length forward FFT of P (length 2^23)
    fft_pass<3><<<1024, b, 0, stream>>>(nullptr, nullptr, buf0, buf1, nullptr);
    fft_pass<4><<<1024, b, 0, stream>>>(nullptr, nullptr, buf1, buf0, nullptr);
    fft_pass<5><<<1024, b, 0, stream>>>(nullptr, nullptr, buf0, nullptr, out2);
}

// Round 10
// 146.014 us; speedup vs baseline: 1.1620x; 1.1620x over previous
//
#include <hip/hip_runtime.h>
#include <hip/hip_fp16.h>

#define N_SIG (1 << 23)   // 8388608
#define N2    (1 << 24)   // padded FFT length = 256^3
#define MH    (1 << 23)   // half length M = 2^23 = 256*256*128

// ---------------------------------------------------------------------------
// packed-f32 complex type: <2 x float> lowers to v_pk_add_f32 / v_pk_fma_f32
// ---------------------------------------------------------------------------
typedef float v2f __attribute__((ext_vector_type(2)));

__device__ __forceinline__ v2f mk(float x, float y) { v2f r; r.x = x; r.y = y; return r; }
__device__ __forceinline__ v2f cadd(v2f a, v2f b) { return a + b; }
__device__ __forceinline__ v2f csub(v2f a, v2f b) { return a - b; }
__device__ __forceinline__ v2f cmul(v2f a, v2f b) {
    // (ax,ax)*b + (-ay,ay)*(by,bx)  -> 2x v_pk_mul/fma
    return mk(a.x, a.x) * b + mk(-a.y, a.y) * __builtin_shufflevector(b, b, 1, 0);
}
__device__ __forceinline__ v2f mulnegi(v2f a) { return mk(a.y, -a.x); }   // -i*a
__device__ __forceinline__ v2f conjv(v2f a)  { return mk(a.x, -a.y); }

__device__ __forceinline__ v2f h2f(__half2 h) {
    return mk(__low2float(h), __high2float(h));
}
__device__ __forceinline__ __half2 f2h(v2f f) {
    return __float22half2_rn(make_float2(f.x, f.y));
}

// exp(-2*pi*i*f), f in revolutions
__device__ __forceinline__ v2f twid(float f) {
    float s, c;
#if __has_builtin(__builtin_amdgcn_sinf) && __has_builtin(__builtin_amdgcn_cosf)
    s = __builtin_amdgcn_sinf(f);
    c = __builtin_amdgcn_cosf(f);
#else
    __sincosf(6.28318530717958647693f * f, &s, &c);
#endif
    return mk(c, -s);
}

// radix-4 DIF butterfly = natural-order 4-point DFT (negative exponent)
__device__ __forceinline__ void bfly4(v2f c0, v2f c1, v2f c2, v2f c3,
                                      v2f& e0, v2f& e1, v2f& e2, v2f& e3) {
    v2f d0 = c0 + c2, d1 = c0 - c2;
    v2f d2 = c1 + c3, d3 = mulnegi(c1 - c3);
    e0 = d0 + d2; e1 = d1 + d3; e2 = d0 - d2; e3 = d1 - d3;
}

// 16-point DFT, natural order in/out
__device__ __forceinline__ void fft16(v2f v[16]) {
    const float C1 = 0.92387953251128675613f;
    const float S1 = 0.38268343236508977173f;
    const float RH = 0.70710678118654752440f;
    const v2f W1 = mk( C1, -S1);
    const v2f W2 = mk( RH, -RH);
    const v2f W3 = mk( S1, -C1);
    const v2f W6 = mk(-RH, -RH);
    const v2f W9 = mk(-C1,  S1);
    v2f t[16];
    { v2f e0,e1,e2,e3; bfly4(v[0],v[4],v[8],v[12], e0,e1,e2,e3);
      t[0]=e0; t[1]=e1; t[2]=e2; t[3]=e3; }
    { v2f e0,e1,e2,e3; bfly4(v[1],v[5],v[9],v[13], e0,e1,e2,e3);
      t[4]=e0; t[5]=cmul(e1,W1); t[6]=cmul(e2,W2); t[7]=cmul(e3,W3); }
    { v2f e0,e1,e2,e3; bfly4(v[2],v[6],v[10],v[14], e0,e1,e2,e3);
      t[8]=e0; t[9]=cmul(e1,W2); t[10]=mulnegi(e2); t[11]=cmul(e3,W6); }
    { v2f e0,e1,e2,e3; bfly4(v[3],v[7],v[11],v[15], e0,e1,e2,e3);
      t[12]=e0; t[13]=cmul(e1,W3); t[14]=cmul(e2,W6); t[15]=cmul(e3,W9); }
    { v2f e0,e1,e2,e3; bfly4(t[0],t[4],t[8],t[12], e0,e1,e2,e3);
      v[0]=e0; v[4]=e1; v[8]=e2; v[12]=e3; }
    { v2f e0,e1,e2,e3; bfly4(t[1],t[5],t[9],t[13], e0,e1,e2,e3);
      v[1]=e0; v[5]=e1; v[9]=e2; v[13]=e3; }
    { v2f e0,e1,e2,e3; bfly4(t[2],t[6],t[10],t[14], e0,e1,e2,e3);
      v[2]=e0; v[6]=e1; v[10]=e2; v[14]=e3; }
    { v2f e0,e1,e2,e3; bfly4(t[3],t[7],t[11],t[15], e0,e1,e2,e3);
      v[3]=e0; v[7]=e1; v[11]=e2; v[15]=e3; }
}

// 8-point DFT, natural order in/out
__device__ __forceinline__ void fft8(v2f v[8]) {
    const float RH = 0.70710678118654752440f;
    v2f e0,e1,e2,e3, o0,o1,o2,o3;
    bfly4(v[0],v[2],v[4],v[6], e0,e1,e2,e3);
    bfly4(v[1],v[3],v[5],v[7], o0,o1,o2,o3);
    o1 = cmul(o1, mk( RH,-RH));
    o2 = mulnegi(o2);
    o3 = cmul(o3, mk(-RH,-RH));
    v[0]=e0+o0; v[4]=e0-o0;
    v[1]=e1+o1; v[5]=e1-o1;
    v[2]=e2+o2; v[6]=e2-o2;
    v[3]=e3+o3; v[7]=e3-o3;
}

// Scaled W for stored Z_s = Z * 2^-2: returns W * 2^-14 = -i*2^-12*(sk^2 - conj(sr)^2)
__device__ __forceinline__ v2f Wfun_s(v2f sk, v2f sr) {
    v2f a2 = cmul(sk, sk);
    v2f cs = conjv(sr);
    v2f b2 = cmul(cs, cs);
    v2f d  = a2 - b2;
    return mulnegi(d) * (1.0f / 4096.0f);
}

// ---------------------------------------------------------------------------
// MODE 0: fwd stage A  (N2, radix-256, l=65536), pack fused, staged j-major out
// MODE 1: fwd stage B  (N2, radix-256, l=256),  direct k-major store
// MODE 2: fwd stage C  (N2, radix-256, l=1),    direct store, Z_s = Z*2^-2
// MODE 3: inv stage A  (M,  radix-256, l=32768), HERMITIAN POINTWISE FUSED in
//         the load (each P computed exactly once), staged out, amp 2^-4
// MODE 4: inv stage B  (M,  radix-256, l=128),  direct store, amp 2^-4
// MODE 5: inv stage C  (M,  radix-128, l=1),    fp32 interleaved-real out, *0.5
// 512 threads; 32 rows x 256 (radix-256) / 64 rows x 128 (radix-128);
// unphased half2 transpose in 32 KiB LDS, ^row swizzle (2-way floor).
// ---------------------------------------------------------------------------
template<int MODE>
__global__ __launch_bounds__(512, 4)
void fft_pass(const float* __restrict__ ga, const float* __restrict__ gx,
              const __half2* __restrict__ gin, __half2* __restrict__ gout,
              float2* __restrict__ goutF) {
    __shared__ __half2 tile[8192];   // 32 KB
    const int t   = threadIdx.x;
    const int blk = blockIdx.x;

    if constexpr (MODE == 5) {
        // ---- radix-128 final pass: 64 rows x 128 pts, slot in [0,8) ----
        const int row  = t & 63;
        const int slot = t >> 6;
        const int swz  = row & 31;
        const int bi   = blk * 64 + row;

        v2f va[8], vb[8];
        #pragma unroll
        for (int u2 = 0; u2 < 8; ++u2)
            va[u2] = h2f(gin[bi + ((slot + 16 * u2) << 16)]);
        #pragma unroll
        for (int u2 = 0; u2 < 8; ++u2)
            vb[u2] = h2f(gin[bi + ((slot + 8 + 16 * u2) << 16)]);
        fft8(va); fft8(vb);
        {   // layer-1 twiddles via recurrence (chain <= 7)
            v2f w1a = twid((float)slot * (1.0f / 128.0f));
            v2f w1b = twid((float)(slot + 8) * (1.0f / 128.0f));
            v2f ca = w1a, cb = w1b;
            va[1] = cmul(va[1], ca); vb[1] = cmul(vb[1], cb);
            #pragma unroll
            for (int r2 = 2; r2 < 8; ++r2) {
                ca = cmul(ca, w1a); va[r2] = cmul(va[r2], ca);
                cb = cmul(cb, w1b); vb[r2] = cmul(vb[r2], cb);
            }
        }
        #pragma unroll
        for (int r2 = 0; r2 < 8; ++r2) {
            tile[row * 128 + ((slot + 16 * r2) ^ swz)] = f2h(va[r2]);
            tile[row * 128 + ((slot + 8 + 16 * r2) ^ swz)] = f2h(vb[r2]);
        }
        __syncthreads();
        v2f w[16];
        #pragma unroll
        for (int q1 = 0; q1 < 16; ++q1)
            w[q1] = h2f(tile[row * 128 + ((q1 + 16 * slot) ^ swz)]);
        fft16(w);   // w[r1] -> output r = slot + 8*r1

        const float sc = 0.5f;          // accumulated scale 2^-22; y = G/2^23
        const int k0 = blk * 64;
        #pragma unroll
        for (int r1 = 0; r1 < 8; ++r1) {
            int r = slot + 8 * r1;      // < 64
            goutF[k0 + row + (r << 16)] = make_float2(w[r1].x * sc, -w[r1].y * sc);
        }
        return;
    } else {
        // ---- radix-256 pass: 32 rows x 256 pts, slot in [0,16) ----
        const int row  = t & 31;
        const int slot = t >> 5;
        v2f v[16];
        int jt = 0;

        if constexpr (MODE == 0) {          // fwd A, pack fused (q>=128 zero)
            int j = blk * 32 + row;
            jt = j;
            #pragma unroll
            for (int u2 = 0; u2 < 16; ++u2) {
                if (u2 < 8) {
                    int g = j + ((slot + 16 * u2) << 16);   // < N_SIG
                    v[u2] = mk(ga[g], gx[g]);
                } else {
                    v[u2] = mk(0.f, 0.f);
                }
            }
        } else if constexpr (MODE == 3) {   // inv A: Hermitian pointwise FUSED
            int j = blk * 32 + row;          // j in [0, 2^15)
            jt = j;
            #pragma unroll
            for (int u2 = 0; u2 < 16; ++u2) {
                int tp = j + ((slot + 16 * u2) << 15);       // [0, M)
                v2f z1 = h2f(gin[tp]);                       // Z[t]
                v2f z2 = h2f(gin[tp + MH]);                  // Z[t+M]
                v2f z3 = h2f(gin[(N2 - tp) & (N2 - 1)]);     // Z[N2-t]
                v2f z4 = h2f(gin[MH - tp]);                  // Z[M-t]
                v2f Wt  = Wfun_s(z1, z3);                    // W[t]   * 2^-14
                v2f WtM = Wfun_s(z2, z4);                    // W[t+M] * 2^-14
                v2f S = (Wt + WtM) * 0.5f;
                v2f D = (Wt - WtM) * 0.5f;
                v2f e = twid((float)tp * (1.0f / 16777216.0f));
                v2f T = cmul(conjv(e), D);                   // e^{+i th} * D
                v2f U = S + mk(-T.y, T.x);                   // S + i*T
                v[u2] = conjv(U);                            // P_s[t]
            }
        } else if constexpr (MODE == 1) {   // fwd B
            int jB = blk >> 3, k0 = (blk & 7) * 32;
            int bi = k0 + row + (jB << 8);
            jt = jB;
            #pragma unroll
            for (int u2 = 0; u2 < 16; ++u2)
                v[u2] = h2f(gin[bi + ((slot + 16 * u2) << 16)]);
        } else if constexpr (MODE == 4) {   // inv B (half length, stride 2^15)
            int jB = blk >> 3, k0 = (blk & 7) * 32;
            int bi = k0 + row + (jB << 8);
            jt = jB;
            #pragma unroll
            for (int u2 = 0; u2 < 16; ++u2)
                v[u2] = h2f(gin[bi + ((slot + 16 * u2) << 15)]);
        } else {                            // MODE 2: fwd C
            int bi = blk * 32 + row;
            #pragma unroll
            for (int u2 = 0; u2 < 16; ++u2)
                v[u2] = h2f(gin[bi + ((slot + 16 * u2) << 16)]);
        }

        // layer 1: FFT16 over u2, twiddle W256^{slot*r}, reseed at r=8
        fft16(v);
        {
            v2f w1 = twid((float)slot * (1.0f / 256.0f));
            v2f w8 = twid((float)slot * (1.0f / 32.0f));
            v2f cw = w1;
            v[1] = cmul(v[1], cw);
            #pragma unroll
            for (int r = 2; r < 16; ++r) {
                cw = (r == 8) ? w8 : cmul(cw, w1);
                v[r] = cmul(v[r], cw);
            }
        }

        // unphased half2 transpose, ^row swizzle
        #pragma unroll
        for (int r = 0; r < 16; ++r)
            tile[row * 256 + ((slot + 16 * r) ^ row)] = f2h(v[r]);
        __syncthreads();
        v2f w[16];
        #pragma unroll
        for (int u1 = 0; u1 < 16; ++u1)
            w[u1] = h2f(tile[row * 256 + ((u1 + 16 * slot) ^ row)]);
        if constexpr (MODE == 0 || MODE == 3)
            __syncthreads();                 // readers done before staging overwrite

        fft16(w);

        // outer twiddle base*step^v2 (reseed at v2=8); MODE3/4 fold 2^-4 scale
        {
            float base_rev, step_rev, amp;
            if constexpr (MODE == 0) {       // D = 2^24
                base_rev = (float)(jt * slot) * (1.0f / 16777216.0f);
                step_rev = (float)jt * (1.0f / 1048576.0f);
                amp = 1.0f;
            } else if constexpr (MODE == 3) {// D = 2^23
                base_rev = (float)(jt * slot) * (1.0f / 8388608.0f);
                step_rev = (float)jt * (1.0f / 524288.0f);
                amp = 0.0625f;
            } else if constexpr (MODE == 1) {// D = 65536
                base_rev = (float)(jt * slot) * (1.0f / 65536.0f);
                step_rev = (float)jt * (1.0f / 4096.0f);
                amp = 1.0f;
            } else {                         // MODE 2 unused / MODE 4: D = 32768
                base_rev = (float)(jt * slot) * (1.0f / 32768.0f);
                step_rev = (float)jt * (1.0f / 2048.0f);
                amp = 0.0625f;
            }
            if constexpr (MODE != 2) {
                v2f b0 = twid(base_rev) * amp;
                v2f os = twid(step_rev);
                v2f b8 = twid(base_rev + 8.0f * step_rev) * amp;
                v2f ob = b0;
                w[0] = cmul(w[0], ob);
                #pragma unroll
                for (int v2 = 1; v2 < 16; ++v2) {
                    ob = (v2 == 8) ? b8 : cmul(ob, os);
                    w[v2] = cmul(w[v2], ob);
                }
            }
        }

        if constexpr (MODE == 0 || MODE == 3) {
            // j-major out[256 j + r]: stage half2, one linear sweep
            #pragma unroll
            for (int v2 = 0; v2 < 16; ++v2)
                tile[row * 256 + ((slot + 16 * v2) ^ row)] = f2h(w[v2]);
            __syncthreads();
            int base = blk << 13;
            #pragma unroll
            for (int i = 0; i < 16; ++i) {
                int s = t + 512 * i;
                int rr = s >> 8, c = s & 255;
                gout[base + s] = tile[rr * 256 + (c ^ (rr & 31))];
            }
        } else if constexpr (MODE == 1 || MODE == 4) {
            // k-major out[k + 65536 j + 256 r]: direct store (32-wide runs)
            int jB = blk >> 3, k0 = (blk & 7) * 32;
            int base = k0 + (jB << 16) + row;
            #pragma unroll
            for (int v2 = 0; v2 < 16; ++v2)
                gout[base + ((slot + 16 * v2) << 8)] = f2h(w[v2]);
        } else {
            // MODE 2: out[k + 65536 r]: direct store, Z_s = Z * 2^-2
            int base = blk * 32 + row;
            #pragma unroll
            for (int v2 = 0; v2 < 16; ++v2)
                gout[base + ((slot + 16 * v2) << 16)] = f2h(w[v2] * 0.25f);
        }
    }
}

extern "C" void kernel_launch(void* const* d_in, const int* in_sizes, int n_in,
                              void* d_out, int out_size, void* d_ws, size_t ws_size,
                              hipStream_t stream) {
    const float* a = (const float*)d_in[0];
    const float* x = (const float*)d_in[1];
    float2* out2 = (float2*)d_out;

    __half2* buf0 = (__half2*)d_ws;     // 64 MB
    __half2* buf1 = buf0 + N2;          // 64 MB

    dim3 b(512);
    // forward FFT of z = a + i*x, length 2^24
    fft_pass<0><<<2048, b, 0, stream>>>(a, x, nullptr, buf0, nullptr);
    fft_pass<1><<<2048, b, 0, stream>>>(nullptr, nullptr, buf0, buf1, nullptr);
    fft_pass<2><<<2048, b, 0, stream>>>(nullptr, nullptr, buf1, buf0, nullptr);
    // inverse via half-length forward FFT; Hermitian pointwise fused into the
    // stage-A load (each P computed exactly once; Z mirror reads are L3-resident)
    fft_pass<3><<<1024, b, 0, stream>>>(nullptr, nullptr, buf0, buf1, nullptr);
    fft_pass<4><<<1024, b, 0, stream>>>(nullptr, nullptr, buf1, buf0, nullptr);
    fft_pass<5><<<1024, b, 0, stream>>>(nullptr, nullptr, buf0, nullptr, out2);
}